// Round 3
// baseline (542.080 us; speedup 1.0000x reference)
//
#include <hip/hip_runtime.h>

// Problem constants (from setup_inputs): vol [2,160,192,224,1] f32, flow [2,160,192,224,3] f32
// Output: warped [2,160,192,224,1] then trf==flow [2,160,192,224,3], concatenated flat f32.
#define BB 2
#define DD 160
#define HH 192
#define WW 224

constexpr int VOXB   = DD * HH * WW;          // voxels per batch = 6,881,280
constexpr int NVOX   = BB * VOXB;             // total voxels     = 13,762,560
constexpr int NGROUP = NVOX / 4;              // 4 voxels / thread = 3,440,640

// Native vector type: __builtin_nontemporal_load/store require a scalar or
// native vector pointee (HIP's float4 is a struct wrapper and may not compile).
typedef float f32x4 __attribute__((ext_vector_type(4)));

struct DimS { int i0, i1; float wlo, whi; };

__device__ __forceinline__ DimS dimcalc(float loc, float mx) {
    // neurite interpn fill_value=None (edge clamp) semantics:
    // cloc = clip(loc,0,mx); l0 = clip(floor(loc),0,mx); l1 = clip(l0+1,0,mx)
    // w_lo = l1 - cloc ; w_hi = 1 - w_lo
    float cl = fminf(fmaxf(loc, 0.0f), mx);
    float l0 = fminf(fmaxf(floorf(loc), 0.0f), mx);
    float l1 = fminf(l0 + 1.0f, mx);
    DimS d;
    d.i0  = (int)l0;
    d.i1  = (int)l1;
    d.wlo = l1 - cl;
    d.whi = 1.0f - d.wlo;
    return d;
}

__global__ __launch_bounds__(256) void st_warp_kernel(
    const float* __restrict__ vol,
    const float* __restrict__ flow,
    float* __restrict__ out_warp,
    float* __restrict__ out_flow)
{
    int g = blockIdx.x * blockDim.x + threadIdx.x;
    if (g >= NGROUP) return;

    const int i0 = g * 4;                 // first voxel of this 4-group
    const int b  = i0 / VOXB;
    const int r  = i0 % VOXB;
    const int z  = r / (HH * WW);
    const int r2 = r % (HH * WW);
    const int y  = r2 / WW;
    const int x0 = r2 % WW;               // WW % 4 == 0 -> group shares b,z,y

    // flow for 4 voxels: 12 consecutive floats, 16B-aligned.
    // Streaming data touched exactly once -> non-temporal (keep L2/L3 for vol).
    const f32x4* fl = reinterpret_cast<const f32x4*>(flow) + (size_t)g * 3;
    const f32x4 fA = __builtin_nontemporal_load(fl + 0);
    const f32x4 fB = __builtin_nontemporal_load(fl + 1);
    const f32x4 fC = __builtin_nontemporal_load(fl + 2);
    const float fr[12] = {fA.x, fA.y, fA.z, fA.w,
                          fB.x, fB.y, fB.z, fB.w,
                          fC.x, fC.y, fC.z, fC.w};

    const float* volb = vol + (size_t)b * VOXB;

    float res[4];
#pragma unroll
    for (int j = 0; j < 4; ++j) {
        const float lz = (float)z        + fr[j * 3 + 0];
        const float ly = (float)y        + fr[j * 3 + 1];
        const float lx = (float)(x0 + j) + fr[j * 3 + 2];

        const DimS dz = dimcalc(lz, (float)(DD - 1));
        const DimS dy = dimcalc(ly, (float)(HH - 1));
        const DimS dx = dimcalc(lx, (float)(WW - 1));

        const float* p00 = volb + ((size_t)dz.i0 * HH + dy.i0) * WW;
        const float* p01 = volb + ((size_t)dz.i0 * HH + dy.i1) * WW;
        const float* p10 = volb + ((size_t)dz.i1 * HH + dy.i0) * WW;
        const float* p11 = volb + ((size_t)dz.i1 * HH + dy.i1) * WW;

        const float v000 = p00[dx.i0], v001 = p00[dx.i1];
        const float v010 = p01[dx.i0], v011 = p01[dx.i1];
        const float v100 = p10[dx.i0], v101 = p10[dx.i1];
        const float v110 = p11[dx.i0], v111 = p11[dx.i1];

        const float vx00 = v000 * dx.wlo + v001 * dx.whi;
        const float vx01 = v010 * dx.wlo + v011 * dx.whi;
        const float vx10 = v100 * dx.wlo + v101 * dx.whi;
        const float vx11 = v110 * dx.wlo + v111 * dx.whi;
        const float vy0  = vx00 * dy.wlo + vx01 * dy.whi;
        const float vy1  = vx10 * dy.wlo + vx11 * dy.whi;
        res[j] = vy0 * dz.wlo + vy1 * dz.whi;
    }

    // warped output (16B, coalesced, write-once -> non-temporal)
    f32x4 ov;
    ov.x = res[0]; ov.y = res[1]; ov.z = res[2]; ov.w = res[3];
    __builtin_nontemporal_store(ov, reinterpret_cast<f32x4*>(out_warp) + g);

    // trf output = flow passthrough (already in registers, write-once -> non-temporal)
    f32x4* of = reinterpret_cast<f32x4*>(out_flow) + (size_t)g * 3;
    __builtin_nontemporal_store(fA, of + 0);
    __builtin_nontemporal_store(fB, of + 1);
    __builtin_nontemporal_store(fC, of + 2);
}

extern "C" void kernel_launch(void* const* d_in, const int* in_sizes, int n_in,
                              void* d_out, int out_size, void* d_ws, size_t ws_size,
                              hipStream_t stream) {
    const float* vol  = (const float*)d_in[0];
    const float* flow = (const float*)d_in[1];
    float* out_warp = (float*)d_out;          // NVOX floats
    float* out_flow = (float*)d_out + NVOX;   // 3*NVOX floats

    const int block = 256;
    const int grid  = (NGROUP + block - 1) / block;  // 13,440 blocks
    st_warp_kernel<<<grid, block, 0, stream>>>(vol, flow, out_warp, out_flow);
}

// Round 4
// 495.430 us; speedup vs baseline: 1.0942x; 1.0942x over previous
//
#include <hip/hip_runtime.h>

// vol [2,160,192,224,1] f32, flow [2,160,192,224,3] f32
// out = warped [2,160,192,224,1] ++ trf(=flow) [2,160,192,224,3], flat f32.
#define DD 160
#define HH 192
#define WW 224

constexpr int BB       = 2;
constexpr int VOXB     = DD * HH * WW;        // 6,881,280
constexpr int NVOX     = BB * VOXB;           // 13,762,560
constexpr int NGROUP   = NVOX / 4;            // 3,440,640 threads, 4 voxels each
constexpr int NWG      = NGROUP / 256;        // 13,440 workgroups (exact)
constexpr int NXCD     = 8;
constexpr int WG_PER_XCD = NWG / NXCD;        // 1,680 (exact -> bijective swizzle)

typedef float f32x4 __attribute__((ext_vector_type(4)));

// 8B pair load, only 4B-aligned in general -> memcpy (defined behavior; clang
// emits the widest legal load, dwordx2 where alignment rules allow).
struct F2 { float lo, hi; };
__device__ __forceinline__ F2 load_pair(const float* __restrict__ p) {
    F2 r;
    __builtin_memcpy(&r, p, sizeof(F2));
    return r;
}

struct DimW { int i0, i1; float wlo, whi; };

// neurite interpn fill_value=None (edge clamp):
// cl = clip(loc,0,mx); l0 = clip(floor(loc),0,mx); l1 = clip(l0+1,0,mx)
// wlo = l1 - cl ; whi = 1 - wlo.  Note: loc >= mx  =>  wlo == 0 exactly.
__device__ __forceinline__ DimW dimcalc(float loc, float mx) {
    float cl = fminf(fmaxf(loc, 0.0f), mx);
    float l0 = fminf(fmaxf(floorf(loc), 0.0f), mx);
    float l1 = fminf(l0 + 1.0f, mx);
    DimW d;
    d.i0  = (int)l0;
    d.i1  = (int)l1;
    d.wlo = l1 - cl;
    d.whi = 1.0f - d.wlo;
    return d;
}

// min-waves/EU = 4: raises the scheduler's register budget (~128 VGPR) so all
// 16 pair-loads can be issued before the first s_waitcnt (MLP), instead of the
// 32-VGPR max-occupancy allocation that serialized them (R3 counters).
__global__ __launch_bounds__(256, 4) void st_warp_kernel(
    const float* __restrict__ vol,
    const float* __restrict__ flow,
    float* __restrict__ out_warp,
    float* __restrict__ out_flow)
{
    // XCD-chunked swizzle: consecutive hardware blockIdx round-robin across the
    // 8 XCDs; remap so each XCD owns a contiguous z-span -> z+1/y+1 vol-plane
    // re-reads hit the same XCD's L2. 13440 % 8 == 0 -> bijective.
    const int wg  = blockIdx.x;
    const int swz = (wg & 7) * WG_PER_XCD + (wg >> 3);
    const int g   = swz * 256 + (int)threadIdx.x;   // grid is exact, no tail

    const int i0 = g * 4;                 // first voxel of this 4-group
    const int b  = i0 / VOXB;
    const int r  = i0 % VOXB;
    const int z  = r / (HH * WW);
    const int r2 = r % (HH * WW);
    const int y  = r2 / WW;
    const int x0 = r2 % WW;               // WW % 4 == 0 -> group shares b,z,y

    // flow: 12 consecutive floats, 16B-aligned; streamed once -> non-temporal.
    const f32x4* fl = reinterpret_cast<const f32x4*>(flow) + (size_t)g * 3;
    const f32x4 fA = __builtin_nontemporal_load(fl + 0);
    const f32x4 fB = __builtin_nontemporal_load(fl + 1);
    const f32x4 fC = __builtin_nontemporal_load(fl + 2);
    const float fr[12] = {fA.x, fA.y, fA.z, fA.w,
                          fB.x, fB.y, fB.z, fB.w,
                          fC.x, fC.y, fC.z, fC.w};

    const float* __restrict__ volb = vol + (size_t)b * VOXB;

    // ---- phase 1: all indices + weights (no loads yet) ----
    DimW dz[4], dy[4];
    int   xb[4];
    float wxlo[4], wxhi[4];
#pragma unroll
    for (int j = 0; j < 4; ++j) {
        const float lz = (float)z        + fr[j * 3 + 0];
        const float ly = (float)y        + fr[j * 3 + 1];
        const float lx = (float)(x0 + j) + fr[j * 3 + 2];
        dz[j] = dimcalc(lz, (float)(DD - 1));
        dy[j] = dimcalc(ly, (float)(HH - 1));
        DimW dx = dimcalc(lx, (float)(WW - 1));
        // pair-load base: elements [xb, xb+1] cover {idx0, idx1}. When
        // idx0 == W-1 the low element is wrong-but-zero-weighted (wlo==0).
        xb[j]   = min(dx.i0, WW - 2);
        wxlo[j] = dx.wlo;
        wxhi[j] = dx.whi;
    }

    // ---- phase 2: issue all 16 pair-loads (independent -> stay in flight) ----
    F2 e[4][4];   // [voxel][corner: (z0,y0),(z0,y1),(z1,y0),(z1,y1)]
#pragma unroll
    for (int j = 0; j < 4; ++j) {
        const int rz0 = dz[j].i0 * HH;
        const int rz1 = dz[j].i1 * HH;
        e[j][0] = load_pair(volb + (rz0 + dy[j].i0) * WW + xb[j]);
        e[j][1] = load_pair(volb + (rz0 + dy[j].i1) * WW + xb[j]);
        e[j][2] = load_pair(volb + (rz1 + dy[j].i0) * WW + xb[j]);
        e[j][3] = load_pair(volb + (rz1 + dy[j].i1) * WW + xb[j]);
    }

    // ---- phase 3: trilinear combine ----
    float res[4];
#pragma unroll
    for (int j = 0; j < 4; ++j) {
        const float vx00 = e[j][0].lo * wxlo[j] + e[j][0].hi * wxhi[j];
        const float vx01 = e[j][1].lo * wxlo[j] + e[j][1].hi * wxhi[j];
        const float vx10 = e[j][2].lo * wxlo[j] + e[j][2].hi * wxhi[j];
        const float vx11 = e[j][3].lo * wxlo[j] + e[j][3].hi * wxhi[j];
        const float vy0  = vx00 * dy[j].wlo + vx01 * dy[j].whi;
        const float vy1  = vx10 * dy[j].wlo + vx11 * dy[j].whi;
        res[j] = vy0 * dz[j].wlo + vy1 * dz[j].whi;
    }

    // warped output (16B, coalesced, write-once -> non-temporal)
    f32x4 ov;
    ov.x = res[0]; ov.y = res[1]; ov.z = res[2]; ov.w = res[3];
    __builtin_nontemporal_store(ov, reinterpret_cast<f32x4*>(out_warp) + g);

    // trf output = flow passthrough (already in registers)
    f32x4* of = reinterpret_cast<f32x4*>(out_flow) + (size_t)g * 3;
    __builtin_nontemporal_store(fA, of + 0);
    __builtin_nontemporal_store(fB, of + 1);
    __builtin_nontemporal_store(fC, of + 2);
}

extern "C" void kernel_launch(void* const* d_in, const int* in_sizes, int n_in,
                              void* d_out, int out_size, void* d_ws, size_t ws_size,
                              hipStream_t stream) {
    const float* vol  = (const float*)d_in[0];
    const float* flow = (const float*)d_in[1];
    float* out_warp = (float*)d_out;          // NVOX floats
    float* out_flow = (float*)d_out + NVOX;   // 3*NVOX floats

    st_warp_kernel<<<NWG, 256, 0, stream>>>(vol, flow, out_warp, out_flow);
}